// Round 2
// baseline (39434.988 us; speedup 1.0000x reference)
//
#include <hip/hip_runtime.h>
#include <math.h>

// Problem constants
#define Hn     1024
#define Bn     256
#define Tn     128
#define Vn     16384
#define DELTAn 16
#define Kn     5
#define QLn    128

// ---------------------------------------------------------------------------
// Generic fp32 GEMM:  Y = A @ W^T  (+ A2 @ W2^T) + bias1 (+ bias2)
//   A : M x K1 rows with leading dim lda (elements)
//   W : N x K1 row-major (leading dim = K1)
//   A2/W2 optional second operand pair (K2), used for x@wih^T + h@whh^T
// Tile: BM=BN=64, BK=16, 256 threads, 4x4 microtile per thread.
// All of M,N multiples of 64; K multiples of 16 (holds for every call here).
// ---------------------------------------------------------------------------
__global__ __launch_bounds__(256) void gemm_nt(
    const float* __restrict__ A, int lda, const float* __restrict__ W, int K1,
    const float* __restrict__ A2, int lda2, const float* __restrict__ W2, int K2,
    const float* __restrict__ bias1, const float* __restrict__ bias2,
    float* __restrict__ Y, int ldy)
{
    __shared__ float As[16][68];   // [k][m], +4 pad keeps float4 alignment
    __shared__ float Bs[16][68];   // [k][n]
    const int bm  = blockIdx.y << 6;
    const int bn  = blockIdx.x << 6;
    const int tid = threadIdx.x;
    const int tx  = (tid & 15) << 2;   // n offset of 4x4 microtile
    const int ty  = (tid >> 4) << 2;   // m offset
    const int lm  = tid >> 2;          // load row 0..63
    const int lk  = (tid & 3) << 2;    // load k offset 0,4,8,12

    float acc[4][4] = {};

    for (int phase = 0; phase < 2; ++phase) {
        const float* Ap   = phase ? A2   : A;
        const float* Wp   = phase ? W2   : W;
        const int    ldap = phase ? lda2 : lda;
        const int    Kp   = phase ? K2   : K1;
        if (Ap == nullptr || Kp == 0) continue;

        const float* arow = Ap + (size_t)(bm + lm) * ldap + lk;
        const float* brow = Wp + (size_t)(bn + lm) * Kp  + lk;

        for (int kt = 0; kt < Kp; kt += 16) {
            float4 av = *(const float4*)(arow + kt);
            float4 bv = *(const float4*)(brow + kt);
            __syncthreads();
            As[lk + 0][lm] = av.x; As[lk + 1][lm] = av.y;
            As[lk + 2][lm] = av.z; As[lk + 3][lm] = av.w;
            Bs[lk + 0][lm] = bv.x; Bs[lk + 1][lm] = bv.y;
            Bs[lk + 2][lm] = bv.z; Bs[lk + 3][lm] = bv.w;
            __syncthreads();
            #pragma unroll
            for (int k = 0; k < 16; ++k) {
                float4 a = *(const float4*)(&As[k][ty]);
                float4 b = *(const float4*)(&Bs[k][tx]);
                acc[0][0] += a.x * b.x; acc[0][1] += a.x * b.y;
                acc[0][2] += a.x * b.z; acc[0][3] += a.x * b.w;
                acc[1][0] += a.y * b.x; acc[1][1] += a.y * b.y;
                acc[1][2] += a.y * b.z; acc[1][3] += a.y * b.w;
                acc[2][0] += a.z * b.x; acc[2][1] += a.z * b.y;
                acc[2][2] += a.z * b.z; acc[2][3] += a.z * b.w;
                acc[3][0] += a.w * b.x; acc[3][1] += a.w * b.y;
                acc[3][2] += a.w * b.z; acc[3][3] += a.w * b.w;
            }
        }
    }

    const int n = bn + tx;
    #pragma unroll
    for (int i = 0; i < 4; ++i) {
        float4 v = make_float4(acc[i][0], acc[i][1], acc[i][2], acc[i][3]);
        if (bias1) { v.x += bias1[n]; v.y += bias1[n + 1]; v.z += bias1[n + 2]; v.w += bias1[n + 3]; }
        if (bias2) { v.x += bias2[n]; v.y += bias2[n + 1]; v.z += bias2[n + 2]; v.w += bias2[n + 3]; }
        *(float4*)(Y + (size_t)(bm + ty + i) * ldy + n) = v;
    }
}

// ---------------------------------------------------------------------------
// LSTM gate nonlinearity + state update.
// g: (nrows, 4H) pre-activations laid out [i | f | g | o] along last dim.
// Updates h, c in place; optionally stores h to yout (row stride ystride).
// ---------------------------------------------------------------------------
__global__ __launch_bounds__(256) void lstm_gates(
    const float* __restrict__ g, float* __restrict__ h, float* __restrict__ c,
    float* __restrict__ yout, int ystride, int nrows)
{
    int idx = blockIdx.x * blockDim.x + threadIdx.x;
    if (idx >= nrows * Hn) return;
    int b = idx >> 10;
    int j = idx & (Hn - 1);
    const float* gr = g + (size_t)b * (4 * Hn);
    float gi = gr[j];
    float gf = gr[Hn + j];
    float gg = gr[2 * Hn + j];
    float go = gr[3 * Hn + j];
    float cv = c[idx];
    float si = 1.0f / (1.0f + expf(-gi));
    float sf = 1.0f / (1.0f + expf(-gf));
    float so = 1.0f / (1.0f + expf(-go));
    float cn = sf * cv + si * tanhf(gg);
    float hn = so * tanhf(cn);
    c[idx] = cn;
    h[idx] = hn;
    if (yout) yout[(size_t)b * ystride + j] = hn;
}

// ---------------------------------------------------------------------------
// Per-row top-k (k=5 or 1) over V=16384 scores; writes decoded indices and
// the next-step embedding emb[b,:] = [fqw_w[:,fw0]+fqw_b ; fql_w[:,fl0]+fql_b].
// One block (256 threads) per batch row. Tie-break: lowest index (lax.top_k).
// ---------------------------------------------------------------------------
__global__ __launch_bounds__(256) void beam_kernel(
    const float* __restrict__ scores, float* __restrict__ decoded,
    float* __restrict__ emb,
    const float* __restrict__ fqw_w, const float* __restrict__ fqw_b,
    const float* __restrict__ fql_w, const float* __restrict__ fql_b,
    int step, int kcur)
{
    __shared__ float svals[256];
    __shared__ int   sidx[256];
    __shared__ int   sel[Kn];
    const int b   = blockIdx.x;
    const int tid = threadIdx.x;
    const float* row = scores + (size_t)b * Vn;

    for (int r = 0; r < kcur; ++r) {
        float best = -INFINITY;
        int   bidx = Vn;
        for (int i = tid; i < Vn; i += 256) {
            bool skip = false;
            for (int q = 0; q < r; ++q) if (sel[q] == i) skip = true;
            float v = row[i];
            if (!skip && v > best) { best = v; bidx = i; }
        }
        svals[tid] = best; sidx[tid] = bidx;
        __syncthreads();
        for (int s = 128; s > 0; s >>= 1) {
            if (tid < s) {
                float v2 = svals[tid + s]; int i2 = sidx[tid + s];
                if (v2 > svals[tid] || (v2 == svals[tid] && i2 < sidx[tid])) {
                    svals[tid] = v2; sidx[tid] = i2;
                }
            }
            __syncthreads();
        }
        if (tid == 0) sel[r] = sidx[0];
        __syncthreads();
    }

    if (tid < kcur) {
        int s_ = sel[tid];
        int fw = s_ / QLn, fl = s_ % QLn;
        float* dp = decoded + ((size_t)(b * DELTAn + step) * Kn + tid) * 2;
        dp[0] = (float)fl;
        dp[1] = (float)fw;
    }

    const int fw0 = sel[0] / QLn;
    const int fl0 = sel[0] % QLn;
    for (int o = tid; o < 512; o += 256) {
        emb[(size_t)b * Hn + o]       = fqw_w[o * QLn + fw0] + fqw_b[o];
        emb[(size_t)b * Hn + 512 + o] = fql_w[o * QLn + fl0] + fql_b[o];
    }
}

// ---------------------------------------------------------------------------
extern "C" void kernel_launch(void* const* d_in, const int* in_sizes, int n_in,
                              void* d_out, int out_size, void* d_ws, size_t ws_size,
                              hipStream_t stream)
{
    int ii = 0;
    const float* x       = (const float*)d_in[ii++];
    const float* efc1_w  = (const float*)d_in[ii++];
    const float* efc1_b  = (const float*)d_in[ii++];
    const float* efc2_w  = (const float*)d_in[ii++];
    const float* efc2_b  = (const float*)d_in[ii++];
    const float* efc3_w  = (const float*)d_in[ii++];
    const float* efc3_b  = (const float*)d_in[ii++];
    const float* el1_wih = (const float*)d_in[ii++];
    const float* el1_whh = (const float*)d_in[ii++];
    const float* el1_bih = (const float*)d_in[ii++];
    const float* el1_bhh = (const float*)d_in[ii++];
    const float* el2_wih = (const float*)d_in[ii++];
    const float* el2_whh = (const float*)d_in[ii++];
    const float* el2_bih = (const float*)d_in[ii++];
    const float* el2_bhh = (const float*)d_in[ii++];
    const float* dl1_wih = (const float*)d_in[ii++];
    const float* dl1_whh = (const float*)d_in[ii++];
    const float* dl1_bih = (const float*)d_in[ii++];
    const float* dl1_bhh = (const float*)d_in[ii++];
    const float* dl2_wih = (const float*)d_in[ii++];
    const float* dl2_whh = (const float*)d_in[ii++];
    const float* dl2_bih = (const float*)d_in[ii++];
    const float* dl2_bhh = (const float*)d_in[ii++];
    const float* dfc1_w  = (const float*)d_in[ii++];
    const float* dfc1_b  = (const float*)d_in[ii++];
    const float* dfc2_w  = (const float*)d_in[ii++];
    const float* dfc2_b  = (const float*)d_in[ii++];
    const float* dfc3_w  = (const float*)d_in[ii++];
    const float* dfc3_b  = (const float*)d_in[ii++];
    const float* fqw_w   = (const float*)d_in[ii++];
    const float* fqw_b   = (const float*)d_in[ii++];
    const float* fql_w   = (const float*)d_in[ii++];
    const float* fql_b   = (const float*)d_in[ii++];

    float* out = (float*)d_out;

    // Workspace layout (floats) — total 45,088,768 floats = 180.4 MB.
    float* ws     = (float*)d_ws;
    float* buf0   = ws;                              // 32768*1024: e3 sequence
    float* tmp2   = buf0 + (size_t)32768 * 1024;     // 4096*1024 FC chunk temp
    float* scores = tmp2 + (size_t)4096 * 1024;      // 256*16384 (= 4096*1024, doubles as FC chunk temp)
    float* gbuf   = scores + (size_t)256 * Vn;       // 256*4096 gate pre-activations
    float* h1     = gbuf + 256 * 4096;               // 256*1024 each below
    float* c1     = h1 + 256 * 1024;
    float* h2     = c1 + 256 * 1024;
    float* c2     = h2 + 256 * 1024;
    float* y1t    = c2 + 256 * 1024;                 // layer-1 hidden for current step
    float* f1buf  = y1t + 256 * 1024;
    float* f2buf  = f1buf + 256 * 1024;
    float* emb    = f2buf + 256 * 1024;

    auto gemm = [&](const float* A, int lda, const float* W, int K1,
                    const float* A2, int lda2, const float* W2, int K2,
                    const float* b1, const float* b2,
                    float* Y, int ldy, int M, int N) {
        dim3 grid(N / 64, M / 64);
        hipLaunchKernelGGL(gemm_nt, grid, dim3(256), 0, stream,
                           A, lda, W, K1, A2, lda2, W2, K2, b1, b2, Y, ldy);
    };

    const int TH = Tn * Hn;       // 131072, seq-buffer row stride per batch

    // ---- Encoder feedforward, chunked (8 chunks of 4096 rows):
    //      scores = FC1(x_chunk); tmp2 = FC2(scores); buf0_chunk = FC3(tmp2)
    for (int c = 0; c < 8; ++c) {
        const float* xc = x + (size_t)c * 4096 * 64;
        float* e3c = buf0 + (size_t)c * 4096 * 1024;
        gemm(xc,     64, efc1_w, 64, nullptr, 0, nullptr, 0, efc1_b, nullptr, scores, Hn, 4096, Hn);
        gemm(scores, Hn, efc2_w, Hn, nullptr, 0, nullptr, 0, efc2_b, nullptr, tmp2,   Hn, 4096, Hn);
        gemm(tmp2,   Hn, efc3_w, Hn, nullptr, 0, nullptr, 0, efc3_b, nullptr, e3c,    Hn, 4096, Hn);
    }

    // ---- Zero LSTM states (h1,c1,h2,c2 contiguous) ----
    hipMemsetAsync(h1, 0, (size_t)4 * 256 * 1024 * sizeof(float), stream);

    // ---- Encoder LSTMs, layer1+layer2 fused per timestep (no y1 sequence) ----
    for (int t = 0; t < Tn; ++t) {
        gemm(buf0 + (size_t)t * Hn, TH, el1_wih, Hn,
             h1, Hn, el1_whh, Hn,
             el1_bih, el1_bhh, gbuf, 4 * Hn, Bn, 4 * Hn);
        hipLaunchKernelGGL(lstm_gates, dim3(1024), dim3(256), 0, stream,
                           gbuf, h1, c1, y1t, Hn, Bn);
        gemm(y1t, Hn, el2_wih, Hn,
             h2, Hn, el2_whh, Hn,
             el2_bih, el2_bhh, gbuf, 4 * Hn, Bn, 4 * Hn);
        hipLaunchKernelGGL(lstm_gates, dim3(1024), dim3(256), 0, stream,
                           gbuf, h2, c2, (float*)nullptr, 0, Bn);
    }

    // ---- Zero decoded output (untouched slots must be 0) ----
    hipMemsetAsync(out, 0, (size_t)out_size * sizeof(float), stream);

    // ---- Decoder: 16 autoregressive steps ----
    for (int it = 0; it < DELTAn; ++it) {
        const float* xin = (it == 0) ? h2 : emb;
        // dl1 step
        gemm(xin, Hn, dl1_wih, Hn, h1, Hn, dl1_whh, Hn,
             dl1_bih, dl1_bhh, gbuf, 4 * Hn, Bn, 4 * Hn);
        hipLaunchKernelGGL(lstm_gates, dim3(1024), dim3(256), 0, stream,
                           gbuf, h1, c1, (float*)nullptr, 0, Bn);
        // dl2 step
        gemm(h1, Hn, dl2_wih, Hn, h2, Hn, dl2_whh, Hn,
             dl2_bih, dl2_bhh, gbuf, 4 * Hn, Bn, 4 * Hn);
        hipLaunchKernelGGL(lstm_gates, dim3(1024), dim3(256), 0, stream,
                           gbuf, h2, c2, (float*)nullptr, 0, Bn);
        // dfc1 -> dfc2 -> dfc3 (scores)
        gemm(h2,    Hn, dfc1_w, Hn, nullptr, 0, nullptr, 0, dfc1_b, nullptr, f1buf,  Hn, Bn, Hn);
        gemm(f1buf, Hn, dfc2_w, Hn, nullptr, 0, nullptr, 0, dfc2_b, nullptr, f2buf,  Hn, Bn, Hn);
        gemm(f2buf, Hn, dfc3_w, Hn, nullptr, 0, nullptr, 0, dfc3_b, nullptr, scores, Vn, Bn, Vn);
        // top-k + decoded write + next embedding
        hipLaunchKernelGGL(beam_kernel, dim3(Bn), dim3(256), 0, stream,
                           scores, out, emb, fqw_w, fqw_b, fql_w, fql_b,
                           it, (it == 0) ? Kn : 1);
    }
}

// Round 3
// 34852.887 us; speedup vs baseline: 1.1315x; 1.1315x over previous
//
#include <hip/hip_runtime.h>
#include <math.h>

// Problem constants
#define Hn     1024
#define Bn     256
#define Tn     128
#define Vn     16384
#define DELTAn 16
#define Kn     5
#define QLn    128

// ---------------------------------------------------------------------------
// Generic fp32 GEMM:  Y = A @ W^T + bias   (64x64 tile, 4x4 microtile)
// Used for decoder FCs (M=256).
// ---------------------------------------------------------------------------
__global__ __launch_bounds__(256) void gemm_nt(
    const float* __restrict__ A, int lda, const float* __restrict__ W, int K1,
    const float* __restrict__ bias1, float* __restrict__ Y, int ldy)
{
    __shared__ float As[16][68];
    __shared__ float Bs[16][68];
    const int bm  = blockIdx.y << 6;
    const int bn  = blockIdx.x << 6;
    const int tid = threadIdx.x;
    const int tx  = (tid & 15) << 2;
    const int ty  = (tid >> 4) << 2;
    const int lm  = tid >> 2;
    const int lk  = (tid & 3) << 2;

    float acc[4][4] = {};
    const float* arow = A + (size_t)(bm + lm) * lda + lk;
    const float* brow = W + (size_t)(bn + lm) * K1  + lk;

    for (int kt = 0; kt < K1; kt += 16) {
        float4 av = *(const float4*)(arow + kt);
        float4 bv = *(const float4*)(brow + kt);
        __syncthreads();
        As[lk + 0][lm] = av.x; As[lk + 1][lm] = av.y;
        As[lk + 2][lm] = av.z; As[lk + 3][lm] = av.w;
        Bs[lk + 0][lm] = bv.x; Bs[lk + 1][lm] = bv.y;
        Bs[lk + 2][lm] = bv.z; Bs[lk + 3][lm] = bv.w;
        __syncthreads();
        #pragma unroll
        for (int k = 0; k < 16; ++k) {
            float4 a = *(const float4*)(&As[k][ty]);
            float4 b = *(const float4*)(&Bs[k][tx]);
            acc[0][0] += a.x * b.x; acc[0][1] += a.x * b.y;
            acc[0][2] += a.x * b.z; acc[0][3] += a.x * b.w;
            acc[1][0] += a.y * b.x; acc[1][1] += a.y * b.y;
            acc[1][2] += a.y * b.z; acc[1][3] += a.y * b.w;
            acc[2][0] += a.z * b.x; acc[2][1] += a.z * b.y;
            acc[2][2] += a.z * b.z; acc[2][3] += a.z * b.w;
            acc[3][0] += a.w * b.x; acc[3][1] += a.w * b.y;
            acc[3][2] += a.w * b.z; acc[3][3] += a.w * b.w;
        }
    }

    const int n = bn + tx;
    #pragma unroll
    for (int i = 0; i < 4; ++i) {
        float4 v = make_float4(acc[i][0], acc[i][1], acc[i][2], acc[i][3]);
        v.x += bias1[n]; v.y += bias1[n + 1]; v.z += bias1[n + 2]; v.w += bias1[n + 3];
        *(float4*)(Y + (size_t)(bm + ty + i) * ldy + n) = v;
    }
}

// ---------------------------------------------------------------------------
// Big-tile fp32 GEMM: 128x128 tile, 8x8 microtile, 256 threads. VALU-bound
// (0.5 B/FLOP LDS ratio). For encoder FC chain (M=4096 chunks).
// ---------------------------------------------------------------------------
__global__ __launch_bounds__(256) void gemm_nt_128(
    const float* __restrict__ A, int lda, const float* __restrict__ W, int K,
    const float* __restrict__ bias, float* __restrict__ Y, int ldy)
{
    __shared__ float As[16 * 132];
    __shared__ float Bs[16 * 132];
    const int bm   = blockIdx.y << 7;
    const int bn   = blockIdx.x << 7;
    const int tid  = threadIdx.x;
    const int tx   = (tid & 15) << 3;   // col base (8 cols)
    const int ty   = (tid >> 4) << 3;   // row base (8 rows)
    const int lrow = tid >> 1;          // 0..127
    const int lk   = (tid & 1) << 3;    // 0 or 8

    float acc[8][8] = {};
    const float* arow = A + (size_t)(bm + lrow) * lda + lk;
    const float* brow = W + (size_t)(bn + lrow) * K   + lk;

    for (int kt = 0; kt < K; kt += 16) {
        float4 a0 = *(const float4*)(arow + kt);
        float4 a1 = *(const float4*)(arow + kt + 4);
        float4 b0 = *(const float4*)(brow + kt);
        float4 b1 = *(const float4*)(brow + kt + 4);
        __syncthreads();
        As[(lk + 0) * 132 + lrow] = a0.x; As[(lk + 1) * 132 + lrow] = a0.y;
        As[(lk + 2) * 132 + lrow] = a0.z; As[(lk + 3) * 132 + lrow] = a0.w;
        As[(lk + 4) * 132 + lrow] = a1.x; As[(lk + 5) * 132 + lrow] = a1.y;
        As[(lk + 6) * 132 + lrow] = a1.z; As[(lk + 7) * 132 + lrow] = a1.w;
        Bs[(lk + 0) * 132 + lrow] = b0.x; Bs[(lk + 1) * 132 + lrow] = b0.y;
        Bs[(lk + 2) * 132 + lrow] = b0.z; Bs[(lk + 3) * 132 + lrow] = b0.w;
        Bs[(lk + 4) * 132 + lrow] = b1.x; Bs[(lk + 5) * 132 + lrow] = b1.y;
        Bs[(lk + 6) * 132 + lrow] = b1.z; Bs[(lk + 7) * 132 + lrow] = b1.w;
        __syncthreads();
        #pragma unroll
        for (int k = 0; k < 16; ++k) {
            float4 x0 = *(const float4*)(As + k * 132 + ty);
            float4 x1 = *(const float4*)(As + k * 132 + ty + 4);
            float4 y0 = *(const float4*)(Bs + k * 132 + tx);
            float4 y1 = *(const float4*)(Bs + k * 132 + tx + 4);
            float av[8] = {x0.x, x0.y, x0.z, x0.w, x1.x, x1.y, x1.z, x1.w};
            float bv[8] = {y0.x, y0.y, y0.z, y0.w, y1.x, y1.y, y1.z, y1.w};
            #pragma unroll
            for (int i = 0; i < 8; ++i)
                #pragma unroll
                for (int j = 0; j < 8; ++j)
                    acc[i][j] += av[i] * bv[j];
        }
    }

    #pragma unroll
    for (int i = 0; i < 8; ++i) {
        float* yr = Y + (size_t)(bm + ty + i) * ldy + bn + tx;
        float4 v0 = make_float4(acc[i][0] + bias[bn + tx + 0], acc[i][1] + bias[bn + tx + 1],
                                acc[i][2] + bias[bn + tx + 2], acc[i][3] + bias[bn + tx + 3]);
        float4 v1 = make_float4(acc[i][4] + bias[bn + tx + 4], acc[i][5] + bias[bn + tx + 5],
                                acc[i][6] + bias[bn + tx + 6], acc[i][7] + bias[bn + tx + 7]);
        *(float4*)(yr)     = v0;
        *(float4*)(yr + 4) = v1;
    }
}

// ---------------------------------------------------------------------------
// Fused LSTM step: one kernel per (layer, t).
//   g = x @ wih^T + hprev @ whh^T + bih + bhh ; gates inline; update c, hout.
// Block: 512 threads, tile = 64 batch x 16 j (x 4 gates = 64 g-cols, gathered
// W rows {j, j+H, j+2H, j+3H}).  Grid (64 j-tiles, 4 batch-tiles) = 256 blocks.
// hprev is read by all blocks; hout must be a different buffer (ping-pong).
// c is updated in-place (each element touched by exactly one thread).
// ---------------------------------------------------------------------------
__global__ __launch_bounds__(512) void lstm_step(
    const float* __restrict__ A1, int lda1,      // x input (256 rows)
    const float* __restrict__ hprev,             // 256 x 1024
    const float* __restrict__ wih,               // 4096 x 1024
    const float* __restrict__ whh,               // 4096 x 1024
    const float* __restrict__ bih, const float* __restrict__ bhh,
    float* __restrict__ cbuf,                    // 256 x 1024 (in-place)
    float* __restrict__ hout)                    // 256 x 1024
{
    __shared__ float smem[64 * 68];              // As | Bs during K-loop; Ex after
    float* As = smem;                            // [k][row], stride 68, k<16
    float* Bs = smem + 16 * 68;
    const int tid = threadIdx.x;
    const int jt  = blockIdx.x;                  // 0..63  (j group of 16)
    const int bm  = blockIdx.y << 6;             // batch base
    const int tx  = tid & 31;                    // g-col pair: cols 2tx, 2tx+1
    const int ty  = tid >> 5;                    // batch quad: rows 4ty..4ty+3

    const int lrow = (tid & 255) >> 2;           // 0..63 staging row
    const int lkq  = (tid & 3) << 2;             // 0,4,8,12

    float acc[4][2] = {};

    for (int phase = 0; phase < 2; ++phase) {
        const float* Ap   = phase ? hprev : A1;
        const int    ldap = phase ? Hn : lda1;
        const float* Wp   = phase ? whh : wih;
        const float* asrc = Ap + (size_t)(bm + lrow) * ldap + lkq;
        const int    gate = lrow >> 4;
        const int    wrow = gate * Hn + (jt << 4) + (lrow & 15);
        const float* bsrc = Wp + (size_t)wrow * Hn + lkq;

        for (int kt = 0; kt < Hn; kt += 16) {
            float4 v = (tid < 256) ? *(const float4*)(asrc + kt)
                                   : *(const float4*)(bsrc + kt);
            __syncthreads();
            float* dst = (tid < 256 ? As : Bs) + lrow;
            dst[(lkq + 0) * 68] = v.x; dst[(lkq + 1) * 68] = v.y;
            dst[(lkq + 2) * 68] = v.z; dst[(lkq + 3) * 68] = v.w;
            __syncthreads();
            #pragma unroll
            for (int k = 0; k < 16; ++k) {
                float4 a = *(const float4*)(As + k * 68 + (ty << 2));
                float2 b = *(const float2*)(Bs + k * 68 + (tx << 1));
                acc[0][0] += a.x * b.x; acc[0][1] += a.x * b.y;
                acc[1][0] += a.y * b.x; acc[1][1] += a.y * b.y;
                acc[2][0] += a.z * b.x; acc[2][1] += a.z * b.y;
                acc[3][0] += a.w * b.x; acc[3][1] += a.w * b.y;
            }
        }
    }

    // Exchange: Ex[gcol][batch] (stride 68), with biases folded in.
    __syncthreads();
    #pragma unroll
    for (int ni = 0; ni < 2; ++ni) {
        int c    = (tx << 1) + ni;
        int wrow = (c >> 4) * Hn + (jt << 4) + (c & 15);
        float bsum = bih[wrow] + bhh[wrow];
        #pragma unroll
        for (int mi = 0; mi < 4; ++mi)
            smem[c * 68 + (ty << 2) + mi] = acc[mi][ni] + bsum;
    }
    __syncthreads();

    // Gates: 1024 outputs (64 batch x 16 j), 2 per thread.
    #pragma unroll
    for (int s = 0; s < 2; ++s) {
        int o  = tid + (s << 9);
        int bi = o >> 4;
        int jj = o & 15;
        float gi = smem[(jj     ) * 68 + bi];
        float gf = smem[(16 + jj) * 68 + bi];
        float gg = smem[(32 + jj) * 68 + bi];
        float go = smem[(48 + jj) * 68 + bi];
        size_t idx = (size_t)(bm + bi) * Hn + (jt << 4) + jj;
        float cv = cbuf[idx];
        float si = 1.0f / (1.0f + expf(-gi));
        float sf = 1.0f / (1.0f + expf(-gf));
        float so = 1.0f / (1.0f + expf(-go));
        float cn = sf * cv + si * tanhf(gg);
        float hn = so * tanhf(cn);
        cbuf[idx] = cn;
        hout[idx] = hn;
    }
}

// ---------------------------------------------------------------------------
// Per-row top-k over V=16384 scores; writes decoded indices and next-step
// embedding. One block per batch row. Tie-break: lowest index (lax.top_k).
// ---------------------------------------------------------------------------
__global__ __launch_bounds__(256) void beam_kernel(
    const float* __restrict__ scores, float* __restrict__ decoded,
    float* __restrict__ emb,
    const float* __restrict__ fqw_w, const float* __restrict__ fqw_b,
    const float* __restrict__ fql_w, const float* __restrict__ fql_b,
    int step, int kcur)
{
    __shared__ float svals[256];
    __shared__ int   sidx[256];
    __shared__ int   sel[Kn];
    const int b   = blockIdx.x;
    const int tid = threadIdx.x;
    const float* row = scores + (size_t)b * Vn;

    for (int r = 0; r < kcur; ++r) {
        float best = -INFINITY;
        int   bidx = Vn;
        for (int i = tid; i < Vn; i += 256) {
            bool skip = false;
            for (int q = 0; q < r; ++q) if (sel[q] == i) skip = true;
            float v = row[i];
            if (!skip && v > best) { best = v; bidx = i; }
        }
        svals[tid] = best; sidx[tid] = bidx;
        __syncthreads();
        for (int s = 128; s > 0; s >>= 1) {
            if (tid < s) {
                float v2 = svals[tid + s]; int i2 = sidx[tid + s];
                if (v2 > svals[tid] || (v2 == svals[tid] && i2 < sidx[tid])) {
                    svals[tid] = v2; sidx[tid] = i2;
                }
            }
            __syncthreads();
        }
        if (tid == 0) sel[r] = sidx[0];
        __syncthreads();
    }

    if (tid < kcur) {
        int s_ = sel[tid];
        int fw = s_ / QLn, fl = s_ % QLn;
        float* dp = decoded + ((size_t)(b * DELTAn + step) * Kn + tid) * 2;
        dp[0] = (float)fl;
        dp[1] = (float)fw;
    }

    const int fw0 = sel[0] / QLn;
    const int fl0 = sel[0] % QLn;
    for (int o = tid; o < 512; o += 256) {
        emb[(size_t)b * Hn + o]       = fqw_w[o * QLn + fw0] + fqw_b[o];
        emb[(size_t)b * Hn + 512 + o] = fql_w[o * QLn + fl0] + fql_b[o];
    }
}

// ---------------------------------------------------------------------------
extern "C" void kernel_launch(void* const* d_in, const int* in_sizes, int n_in,
                              void* d_out, int out_size, void* d_ws, size_t ws_size,
                              hipStream_t stream)
{
    int ii = 0;
    const float* x       = (const float*)d_in[ii++];
    const float* efc1_w  = (const float*)d_in[ii++];
    const float* efc1_b  = (const float*)d_in[ii++];
    const float* efc2_w  = (const float*)d_in[ii++];
    const float* efc2_b  = (const float*)d_in[ii++];
    const float* efc3_w  = (const float*)d_in[ii++];
    const float* efc3_b  = (const float*)d_in[ii++];
    const float* el1_wih = (const float*)d_in[ii++];
    const float* el1_whh = (const float*)d_in[ii++];
    const float* el1_bih = (const float*)d_in[ii++];
    const float* el1_bhh = (const float*)d_in[ii++];
    const float* el2_wih = (const float*)d_in[ii++];
    const float* el2_whh = (const float*)d_in[ii++];
    const float* el2_bih = (const float*)d_in[ii++];
    const float* el2_bhh = (const float*)d_in[ii++];
    const float* dl1_wih = (const float*)d_in[ii++];
    const float* dl1_whh = (const float*)d_in[ii++];
    const float* dl1_bih = (const float*)d_in[ii++];
    const float* dl1_bhh = (const float*)d_in[ii++];
    const float* dl2_wih = (const float*)d_in[ii++];
    const float* dl2_whh = (const float*)d_in[ii++];
    const float* dl2_bih = (const float*)d_in[ii++];
    const float* dl2_bhh = (const float*)d_in[ii++];
    const float* dfc1_w  = (const float*)d_in[ii++];
    const float* dfc1_b  = (const float*)d_in[ii++];
    const float* dfc2_w  = (const float*)d_in[ii++];
    const float* dfc2_b  = (const float*)d_in[ii++];
    const float* dfc3_w  = (const float*)d_in[ii++];
    const float* dfc3_b  = (const float*)d_in[ii++];
    const float* fqw_w   = (const float*)d_in[ii++];
    const float* fqw_b   = (const float*)d_in[ii++];
    const float* fql_w   = (const float*)d_in[ii++];
    const float* fql_b   = (const float*)d_in[ii++];

    float* out = (float*)d_out;

    // Workspace layout (floats) — ~177 MB total.
    float* ws     = (float*)d_ws;
    float* buf0   = ws;                              // 32768*1024 e3 sequence
    float* tmp2   = buf0 + (size_t)32768 * 1024;     // 4096*1024 FC chunk temp
    float* scores = tmp2 + (size_t)4096 * 1024;      // 256*16384 (doubles as FC temp)
    float* h1a    = scores + (size_t)256 * Vn;       // zeroed block: h1a,h2a,c1,c2
    float* h2a    = h1a + 256 * Hn;
    float* c1     = h2a + 256 * Hn;
    float* c2     = c1  + 256 * Hn;
    float* h1b    = c2  + 256 * Hn;
    float* h2b    = h1b + 256 * Hn;
    float* f1buf  = h2b + 256 * Hn;
    float* f2buf  = f1buf + 256 * Hn;
    float* emb    = f2buf + 256 * Hn;

    const int TH = Tn * Hn;  // 131072

    auto step = [&](const float* xin, int ldx, float* hc, float* hn,
                    const float* wih, const float* whh,
                    const float* bi, const float* bh, float* c) {
        hipLaunchKernelGGL(lstm_step, dim3(64, 4), dim3(512), 0, stream,
                           xin, ldx, hc, wih, whh, bi, bh, c, hn);
    };

    // ---- Encoder FC chain, chunked (8 x 4096 rows) through scores/tmp2 ----
    for (int c = 0; c < 8; ++c) {
        const float* xc  = x    + (size_t)c * 4096 * 64;
        float*       e3c = buf0 + (size_t)c * 4096 * Hn;
        hipLaunchKernelGGL(gemm_nt_128, dim3(8, 32), dim3(256), 0, stream,
                           xc, 64, efc1_w, 64, efc1_b, scores, Hn);
        hipLaunchKernelGGL(gemm_nt_128, dim3(8, 32), dim3(256), 0, stream,
                           scores, Hn, efc2_w, Hn, efc2_b, tmp2, Hn);
        hipLaunchKernelGGL(gemm_nt_128, dim3(8, 32), dim3(256), 0, stream,
                           tmp2, Hn, efc3_w, Hn, efc3_b, e3c, Hn);
    }

    // ---- Zero initial states (h1a,h2a,c1,c2 contiguous) ----
    hipMemsetAsync(h1a, 0, (size_t)4 * 256 * Hn * sizeof(float), stream);

    // ---- Encoder LSTMs, fused step kernels, h ping-pong ----
    float *h1c = h1a, *h1n = h1b, *h2c = h2a, *h2n = h2b;
    for (int t = 0; t < Tn; ++t) {
        step(buf0 + (size_t)t * Hn, TH, h1c, h1n, el1_wih, el1_whh, el1_bih, el1_bhh, c1);
        step(h1n, Hn, h2c, h2n, el2_wih, el2_whh, el2_bih, el2_bhh, c2);
        float* tt;
        tt = h1c; h1c = h1n; h1n = tt;
        tt = h2c; h2c = h2n; h2n = tt;
    }

    // ---- Zero decoded output ----
    hipMemsetAsync(out, 0, (size_t)out_size * sizeof(float), stream);

    // ---- Decoder: 16 autoregressive steps ----
    for (int it = 0; it < DELTAn; ++it) {
        const float* xin = (it == 0) ? h2c : emb;
        step(xin, Hn, h1c, h1n, dl1_wih, dl1_whh, dl1_bih, dl1_bhh, c1);
        step(h1n, Hn, h2c, h2n, dl2_wih, dl2_whh, dl2_bih, dl2_bhh, c2);
        float* tt;
        tt = h1c; h1c = h1n; h1n = tt;
        tt = h2c; h2c = h2n; h2n = tt;

        hipLaunchKernelGGL(gemm_nt, dim3(16, 4), dim3(256), 0, stream,
                           h2c, Hn, dfc1_w, Hn, dfc1_b, f1buf, Hn);
        hipLaunchKernelGGL(gemm_nt, dim3(16, 4), dim3(256), 0, stream,
                           f1buf, Hn, dfc2_w, Hn, dfc2_b, f2buf, Hn);
        hipLaunchKernelGGL(gemm_nt, dim3(256, 4), dim3(256), 0, stream,
                           f2buf, Hn, dfc3_w, Hn, dfc3_b, scores, Vn);
        hipLaunchKernelGGL(beam_kernel, dim3(Bn), dim3(256), 0, stream,
                           scores, out, emb, fqw_w, fqw_b, fql_w, fql_b,
                           it, (it == 0) ? Kn : 1);
    }
}

// Round 4
// 17402.980 us; speedup vs baseline: 2.2660x; 2.0027x over previous
//
#include <hip/hip_runtime.h>
#include <math.h>

// Problem constants
#define Hn     1024
#define Bn     256
#define Tn     128
#define Vn     16384
#define DELTAn 16
#define Kn     5
#define QLn    128

typedef _Float16 h8 __attribute__((ext_vector_type(8)));
typedef _Float16 h4 __attribute__((ext_vector_type(4)));
typedef float    f32x4 __attribute__((ext_vector_type(4)));

// ---------------------------------------------------------------------------
// fp32 GEMM: Y = A @ W^T + bias (64x64 tile, 4x4 microtile). Decoder dfc1/2.
// ---------------------------------------------------------------------------
__global__ __launch_bounds__(256) void gemm_nt(
    const float* __restrict__ A, int lda, const float* __restrict__ W, int K1,
    const float* __restrict__ bias1, float* __restrict__ Y, int ldy)
{
    __shared__ float As[16][68];
    __shared__ float Bs[16][68];
    const int bm  = blockIdx.y << 6;
    const int bn  = blockIdx.x << 6;
    const int tid = threadIdx.x;
    const int tx  = (tid & 15) << 2;
    const int ty  = (tid >> 4) << 2;
    const int lm  = tid >> 2;
    const int lk  = (tid & 3) << 2;

    float acc[4][4] = {};
    const float* arow = A + (size_t)(bm + lm) * lda + lk;
    const float* brow = W + (size_t)(bn + lm) * K1  + lk;

    for (int kt = 0; kt < K1; kt += 16) {
        float4 av = *(const float4*)(arow + kt);
        float4 bv = *(const float4*)(brow + kt);
        __syncthreads();
        As[lk + 0][lm] = av.x; As[lk + 1][lm] = av.y;
        As[lk + 2][lm] = av.z; As[lk + 3][lm] = av.w;
        Bs[lk + 0][lm] = bv.x; Bs[lk + 1][lm] = bv.y;
        Bs[lk + 2][lm] = bv.z; Bs[lk + 3][lm] = bv.w;
        __syncthreads();
        #pragma unroll
        for (int k = 0; k < 16; ++k) {
            float4 a = *(const float4*)(&As[k][ty]);
            float4 b = *(const float4*)(&Bs[k][tx]);
            acc[0][0] += a.x * b.x; acc[0][1] += a.x * b.y;
            acc[0][2] += a.x * b.z; acc[0][3] += a.x * b.w;
            acc[1][0] += a.y * b.x; acc[1][1] += a.y * b.y;
            acc[1][2] += a.y * b.z; acc[1][3] += a.y * b.w;
            acc[2][0] += a.z * b.x; acc[2][1] += a.z * b.y;
            acc[2][2] += a.z * b.z; acc[2][3] += a.z * b.w;
            acc[3][0] += a.w * b.x; acc[3][1] += a.w * b.y;
            acc[3][2] += a.w * b.z; acc[3][3] += a.w * b.w;
        }
    }

    const int n = bn + tx;
    #pragma unroll
    for (int i = 0; i < 4; ++i) {
        float4 v = make_float4(acc[i][0], acc[i][1], acc[i][2], acc[i][3]);
        v.x += bias1[n]; v.y += bias1[n + 1]; v.z += bias1[n + 2]; v.w += bias1[n + 3];
        *(float4*)(Y + (size_t)(bm + ty + i) * ldy + n) = v;
    }
}

// ---------------------------------------------------------------------------
// Big-tile fp32 GEMM: 128x128 tile, 8x8 microtile. If yhi != null, writes
// f16 hi/lo planes instead of fp32 (used by FC3 to feed MFMA LSTM).
// ---------------------------------------------------------------------------
__global__ __launch_bounds__(256) void gemm_nt_128(
    const float* __restrict__ A, int lda, const float* __restrict__ W, int K,
    const float* __restrict__ bias, float* __restrict__ Y, int ldy,
    _Float16* __restrict__ yhi, _Float16* __restrict__ ylo)
{
    __shared__ float As[16 * 132];
    __shared__ float Bs[16 * 132];
    const int bm   = blockIdx.y << 7;
    const int bn   = blockIdx.x << 7;
    const int tid  = threadIdx.x;
    const int tx   = (tid & 15) << 3;
    const int ty   = (tid >> 4) << 3;
    const int lrow = tid >> 1;
    const int lk   = (tid & 1) << 3;

    float acc[8][8] = {};
    const float* arow = A + (size_t)(bm + lrow) * lda + lk;
    const float* brow = W + (size_t)(bn + lrow) * K   + lk;

    for (int kt = 0; kt < K; kt += 16) {
        float4 a0 = *(const float4*)(arow + kt);
        float4 a1 = *(const float4*)(arow + kt + 4);
        float4 b0 = *(const float4*)(brow + kt);
        float4 b1 = *(const float4*)(brow + kt + 4);
        __syncthreads();
        As[(lk + 0) * 132 + lrow] = a0.x; As[(lk + 1) * 132 + lrow] = a0.y;
        As[(lk + 2) * 132 + lrow] = a0.z; As[(lk + 3) * 132 + lrow] = a0.w;
        As[(lk + 4) * 132 + lrow] = a1.x; As[(lk + 5) * 132 + lrow] = a1.y;
        As[(lk + 6) * 132 + lrow] = a1.z; As[(lk + 7) * 132 + lrow] = a1.w;
        Bs[(lk + 0) * 132 + lrow] = b0.x; Bs[(lk + 1) * 132 + lrow] = b0.y;
        Bs[(lk + 2) * 132 + lrow] = b0.z; Bs[(lk + 3) * 132 + lrow] = b0.w;
        Bs[(lk + 4) * 132 + lrow] = b1.x; Bs[(lk + 5) * 132 + lrow] = b1.y;
        Bs[(lk + 6) * 132 + lrow] = b1.z; Bs[(lk + 7) * 132 + lrow] = b1.w;
        __syncthreads();
        #pragma unroll
        for (int k = 0; k < 16; ++k) {
            float4 x0 = *(const float4*)(As + k * 132 + ty);
            float4 x1 = *(const float4*)(As + k * 132 + ty + 4);
            float4 y0 = *(const float4*)(Bs + k * 132 + tx);
            float4 y1 = *(const float4*)(Bs + k * 132 + tx + 4);
            float av[8] = {x0.x, x0.y, x0.z, x0.w, x1.x, x1.y, x1.z, x1.w};
            float bv[8] = {y0.x, y0.y, y0.z, y0.w, y1.x, y1.y, y1.z, y1.w};
            #pragma unroll
            for (int i = 0; i < 8; ++i)
                #pragma unroll
                for (int j = 0; j < 8; ++j)
                    acc[i][j] += av[i] * bv[j];
        }
    }

    if (yhi) {
        #pragma unroll
        for (int i = 0; i < 8; ++i) {
            h8 vh, vl;
            #pragma unroll
            for (int j = 0; j < 8; ++j) {
                float v = acc[i][j] + bias[bn + tx + j];
                _Float16 hh = (_Float16)v;
                vh[j] = hh;
                vl[j] = (_Float16)(v - (float)hh);
            }
            size_t ro = (size_t)(bm + ty + i) * ldy + bn + tx;
            *(h8*)(yhi + ro) = vh;
            *(h8*)(ylo + ro) = vl;
        }
    } else {
        #pragma unroll
        for (int i = 0; i < 8; ++i) {
            float* yr = Y + (size_t)(bm + ty + i) * ldy + bn + tx;
            float4 v0 = make_float4(acc[i][0] + bias[bn + tx + 0], acc[i][1] + bias[bn + tx + 1],
                                    acc[i][2] + bias[bn + tx + 2], acc[i][3] + bias[bn + tx + 3]);
            float4 v1 = make_float4(acc[i][4] + bias[bn + tx + 4], acc[i][5] + bias[bn + tx + 5],
                                    acc[i][6] + bias[bn + tx + 6], acc[i][7] + bias[bn + tx + 7]);
            *(float4*)(yr)     = v0;
            *(float4*)(yr + 4) = v1;
        }
    }
}

// ---------------------------------------------------------------------------
// Weight split: fp32 -> f16 hi + f16 lo planes. n multiple of 4.
// ---------------------------------------------------------------------------
__global__ __launch_bounds__(256) void wconv(
    const float* __restrict__ s, _Float16* __restrict__ dhi,
    _Float16* __restrict__ dlo, int n)
{
    int i = (blockIdx.x * 256 + threadIdx.x) * 4;
    if (i >= n) return;
    float4 v = *(const float4*)(s + i);
    h4 vh, vl;
    _Float16 h0 = (_Float16)v.x; vh[0] = h0; vl[0] = (_Float16)(v.x - (float)h0);
    _Float16 h1 = (_Float16)v.y; vh[1] = h1; vl[1] = (_Float16)(v.y - (float)h1);
    _Float16 h2 = (_Float16)v.z; vh[2] = h2; vl[2] = (_Float16)(v.z - (float)h2);
    _Float16 h3 = (_Float16)v.w; vh[3] = h3; vl[3] = (_Float16)(v.w - (float)h3);
    *(h4*)(dhi + i) = vh;
    *(h4*)(dlo + i) = vl;
}

// ---------------------------------------------------------------------------
// MFMA LSTM step (split-f16, exact to ~2^-22):
//   g = x@wih^T + hprev@whh^T + bih + bhh ; gates in-register; update c,h.
// Grid (64 jt, 4 bt), 256 threads (4 waves). Block tile: 64 batch x 16 j
// (x4 gates = 64 gate-cols, gate-gathered W rows). wslot layout:
// [wih_hi | wih_lo | whh_hi | whh_lo], each 4194304 f16.
// hhi/hlo are ping-pong OUTPUT planes (differ from hphi/hplo inputs).
// ---------------------------------------------------------------------------
__global__ __launch_bounds__(256) void lstm_mfma(
    const _Float16* __restrict__ xhi, const _Float16* __restrict__ xlo, int ldx,
    const _Float16* __restrict__ hphi, const _Float16* __restrict__ hplo,
    const _Float16* __restrict__ wslot,
    const float* __restrict__ bih, const float* __restrict__ bhh,
    float* __restrict__ cbuf, float* __restrict__ hf,
    _Float16* __restrict__ hhi, _Float16* __restrict__ hlo)
{
    __shared__ _Float16 lds[4][64 * 40];   // Xhi, Xlo, Whi, Wlo (pad 40)
    const int tid  = threadIdx.x;
    const int jt   = blockIdx.x;
    const int bm   = blockIdx.y << 6;
    const int lane = tid & 63;
    const int wv   = tid >> 6;
    const int l15  = lane & 15;
    const int quad = lane >> 4;
    const int r    = tid >> 2;            // staging row 0..63
    const int koff = (tid & 3) << 3;      // staging k offset 0,8,16,24
    const int wrow = (r >> 4) * Hn + (jt << 4) + (r & 15);

    f32x4 acc[4];
    #pragma unroll
    for (int nf = 0; nf < 4; ++nf) acc[nf] = (f32x4){0.f, 0.f, 0.f, 0.f};

    h8 rxh, rxl, rwh, rwl;
    {   // preload ks=0 (phase 0, k0=0)
        size_t xoff = (size_t)(bm + r) * ldx + koff;
        rxh = *(const h8*)(xhi + xoff);
        rxl = *(const h8*)(xlo + xoff);
        size_t woff = (size_t)wrow * Hn + koff;
        rwh = *(const h8*)(wslot + woff);
        rwl = *(const h8*)(wslot + 4194304 + woff);
    }

    for (int ks = 0; ks < 64; ++ks) {
        __syncthreads();
        *(h8*)(&lds[0][r * 40 + koff]) = rxh;
        *(h8*)(&lds[1][r * 40 + koff]) = rxl;
        *(h8*)(&lds[2][r * 40 + koff]) = rwh;
        *(h8*)(&lds[3][r * 40 + koff]) = rwl;
        __syncthreads();
        {   // prefetch next kstep (overlaps with MFMA below)
            int ksn = (ks + 1 < 64) ? ks + 1 : ks;
            int ph  = ksn >> 5;
            int k0  = (ksn & 31) << 5;
            const _Float16* xh_ = ph ? hphi : xhi;
            const _Float16* xl_ = ph ? hplo : xlo;
            int ldx_ = ph ? Hn : ldx;
            const _Float16* wb_ = wslot + (size_t)ph * 8388608;
            size_t xoff = (size_t)(bm + r) * ldx_ + k0 + koff;
            rxh = *(const h8*)(xh_ + xoff);
            rxl = *(const h8*)(xl_ + xoff);
            size_t woff = (size_t)wrow * Hn + k0 + koff;
            rwh = *(const h8*)(wb_ + woff);
            rwl = *(const h8*)(wb_ + 4194304 + woff);
        }
        const int am = (wv << 4) + l15;
        h8 axh = *(const h8*)(&lds[0][am * 40 + quad * 8]);
        h8 axl = *(const h8*)(&lds[1][am * 40 + quad * 8]);
        #pragma unroll
        for (int nf = 0; nf < 4; ++nf) {
            const int bn_ = (nf << 4) + l15;
            h8 bh = *(const h8*)(&lds[2][bn_ * 40 + quad * 8]);
            h8 bl = *(const h8*)(&lds[3][bn_ * 40 + quad * 8]);
            acc[nf] = __builtin_amdgcn_mfma_f32_16x16x32_f16(axh, bh, acc[nf], 0, 0, 0);
            acc[nf] = __builtin_amdgcn_mfma_f32_16x16x32_f16(axh, bl, acc[nf], 0, 0, 0);
            acc[nf] = __builtin_amdgcn_mfma_f32_16x16x32_f16(axl, bh, acc[nf], 0, 0, 0);
        }
    }

    // Epilogue: lane holds all 4 gates for (4 batch rows) x (col j=l15).
    float bs[4];
    #pragma unroll
    for (int nf = 0; nf < 4; ++nf) {
        int br = nf * Hn + (jt << 4) + l15;
        bs[nf] = bih[br] + bhh[br];
    }
    #pragma unroll
    for (int rr = 0; rr < 4; ++rr) {
        int m = (wv << 4) + (quad << 2) + rr;
        size_t idx = (size_t)(bm + m) * Hn + (jt << 4) + l15;
        float gi = acc[0][rr] + bs[0];
        float gf = acc[1][rr] + bs[1];
        float gg = acc[2][rr] + bs[2];
        float go = acc[3][rr] + bs[3];
        float cv = cbuf[idx];
        float si = 1.0f / (1.0f + expf(-gi));
        float sf = 1.0f / (1.0f + expf(-gf));
        float so = 1.0f / (1.0f + expf(-go));
        float cn = sf * cv + si * tanhf(gg);
        float hn = so * tanhf(cn);
        cbuf[idx] = cn;
        if (hf) hf[idx] = hn;
        _Float16 hh = (_Float16)hn;
        hhi[idx] = hh;
        hlo[idx] = (_Float16)(hn - (float)hh);
    }
}

// ---------------------------------------------------------------------------
// Per-row top-k over V=16384; writes decoded indices and next-step embedding
// as f16 hi/lo planes. Tie-break: lowest index (lax.top_k).
// ---------------------------------------------------------------------------
__global__ __launch_bounds__(256) void beam_kernel(
    const float* __restrict__ scores, float* __restrict__ decoded,
    _Float16* __restrict__ embhi, _Float16* __restrict__ emblo,
    const float* __restrict__ fqw_w, const float* __restrict__ fqw_b,
    const float* __restrict__ fql_w, const float* __restrict__ fql_b,
    int step, int kcur)
{
    __shared__ float svals[256];
    __shared__ int   sidx[256];
    __shared__ int   sel[Kn];
    const int b   = blockIdx.x;
    const int tid = threadIdx.x;
    const float* row = scores + (size_t)b * Vn;

    for (int rr = 0; rr < kcur; ++rr) {
        float best = -INFINITY;
        int   bidx = Vn;
        for (int i = tid; i < Vn; i += 256) {
            bool skip = false;
            for (int q = 0; q < rr; ++q) if (sel[q] == i) skip = true;
            float v = row[i];
            if (!skip && v > best) { best = v; bidx = i; }
        }
        svals[tid] = best; sidx[tid] = bidx;
        __syncthreads();
        for (int s = 128; s > 0; s >>= 1) {
            if (tid < s) {
                float v2 = svals[tid + s]; int i2 = sidx[tid + s];
                if (v2 > svals[tid] || (v2 == svals[tid] && i2 < sidx[tid])) {
                    svals[tid] = v2; sidx[tid] = i2;
                }
            }
            __syncthreads();
        }
        if (tid == 0) sel[rr] = sidx[0];
        __syncthreads();
    }

    if (tid < kcur) {
        int s_ = sel[tid];
        int fw = s_ / QLn, fl = s_ % QLn;
        float* dp = decoded + ((size_t)(b * DELTAn + step) * Kn + tid) * 2;
        dp[0] = (float)fl;
        dp[1] = (float)fw;
    }

    const int fw0 = sel[0] / QLn;
    const int fl0 = sel[0] % QLn;
    for (int o = tid; o < 512; o += 256) {
        float v0 = fqw_w[o * QLn + fw0] + fqw_b[o];
        float v1 = fql_w[o * QLn + fl0] + fql_b[o];
        _Float16 h0 = (_Float16)v0;
        _Float16 h1 = (_Float16)v1;
        size_t i0 = (size_t)b * Hn + o;
        embhi[i0]       = h0; emblo[i0]       = (_Float16)(v0 - (float)h0);
        embhi[i0 + 512] = h1; emblo[i0 + 512] = (_Float16)(v1 - (float)h1);
    }
}

// ---------------------------------------------------------------------------
extern "C" void kernel_launch(void* const* d_in, const int* in_sizes, int n_in,
                              void* d_out, int out_size, void* d_ws, size_t ws_size,
                              hipStream_t stream)
{
    int ii = 0;
    const float* x       = (const float*)d_in[ii++];
    const float* efc1_w  = (const float*)d_in[ii++];
    const float* efc1_b  = (const float*)d_in[ii++];
    const float* efc2_w  = (const float*)d_in[ii++];
    const float* efc2_b  = (const float*)d_in[ii++];
    const float* efc3_w  = (const float*)d_in[ii++];
    const float* efc3_b  = (const float*)d_in[ii++];
    const float* el1_wih = (const float*)d_in[ii++];
    const float* el1_whh = (const float*)d_in[ii++];
    const float* el1_bih = (const float*)d_in[ii++];
    const float* el1_bhh = (const float*)d_in[ii++];
    const float* el2_wih = (const float*)d_in[ii++];
    const float* el2_whh = (const float*)d_in[ii++];
    const float* el2_bih = (const float*)d_in[ii++];
    const float* el2_bhh = (const float*)d_in[ii++];
    const float* dl1_wih = (const float*)d_in[ii++];
    const float* dl1_whh = (const float*)d_in[ii++];
    const float* dl1_bih = (const float*)d_in[ii++];
    const float* dl1_bhh = (const float*)d_in[ii++];
    const float* dl2_wih = (const float*)d_in[ii++];
    const float* dl2_whh = (const float*)d_in[ii++];
    const float* dl2_bih = (const float*)d_in[ii++];
    const float* dl2_bhh = (const float*)d_in[ii++];
    const float* dfc1_w  = (const float*)d_in[ii++];
    const float* dfc1_b  = (const float*)d_in[ii++];
    const float* dfc2_w  = (const float*)d_in[ii++];
    const float* dfc2_b  = (const float*)d_in[ii++];
    const float* dfc3_w  = (const float*)d_in[ii++];
    const float* dfc3_b  = (const float*)d_in[ii++];
    const float* fqw_w   = (const float*)d_in[ii++];
    const float* fqw_b   = (const float*)d_in[ii++];
    const float* fql_w   = (const float*)d_in[ii++];
    const float* fql_b   = (const float*)d_in[ii++];

    float* out = (float*)d_out;

    // ---- Workspace layout (bytes), total ~218 MB ----
    char* p = (char*)d_ws;
    auto alloc = [&](size_t bytes) { char* q = p; p += (bytes + 255) & ~(size_t)255; return q; };
    _Float16* bufhi = (_Float16*)alloc((size_t)32768 * 1024 * 2);  // 64 MB e3 hi
    _Float16* buflo = (_Float16*)alloc((size_t)32768 * 1024 * 2);  // 64 MB e3 lo
    _Float16* wbuf  = (_Float16*)alloc((size_t)2 * 16777216 * 2);  // 64 MB: 2 slots x 16M f16
    float*    scores= (float*)alloc((size_t)256 * Vn * 4);         // 16.8 MB (FC temp1 too)
    // zero block (one memset): h2f, c1, c2, h1hiA, h1loA, h2hiA, h2loA
    char*  zbase = p;
    float* h2f   = (float*)alloc((size_t)256 * Hn * 4);
    float* c1    = (float*)alloc((size_t)256 * Hn * 4);
    float* c2    = (float*)alloc((size_t)256 * Hn * 4);
    _Float16* h1hiA = (_Float16*)alloc((size_t)256 * Hn * 2);
    _Float16* h1loA = (_Float16*)alloc((size_t)256 * Hn * 2);
    _Float16* h2hiA = (_Float16*)alloc((size_t)256 * Hn * 2);
    _Float16* h2loA = (_Float16*)alloc((size_t)256 * Hn * 2);
    size_t zbytes = (size_t)(p - zbase);
    _Float16* h1hiB = (_Float16*)alloc((size_t)256 * Hn * 2);
    _Float16* h1loB = (_Float16*)alloc((size_t)256 * Hn * 2);
    _Float16* h2hiB = (_Float16*)alloc((size_t)256 * Hn * 2);
    _Float16* h2loB = (_Float16*)alloc((size_t)256 * Hn * 2);
    float* f1buf = (float*)alloc((size_t)256 * Hn * 4);
    float* f2buf = (float*)alloc((size_t)256 * Hn * 4);
    _Float16* embhi = (_Float16*)alloc((size_t)256 * Hn * 2);
    _Float16* emblo = (_Float16*)alloc((size_t)256 * Hn * 2);
    float* wtmp = (float*)wbuf;   // FC temp2 (wbuf free until weight conversion)

    _Float16* slot0 = wbuf;                 // el1 then dl1
    _Float16* slot1 = wbuf + 16777216;      // el2 then dl2
    const int TH = Tn * Hn;  // 131072

    // ---- Encoder FC chain, 8 chunks x 4096 rows (temps: scores, wtmp) ----
    for (int c = 0; c < 8; ++c) {
        const float* xc = x + (size_t)c * 4096 * 64;
        hipLaunchKernelGGL(gemm_nt_128, dim3(8, 32), dim3(256), 0, stream,
                           xc, 64, efc1_w, 64, efc1_b, scores, Hn, (_Float16*)nullptr, (_Float16*)nullptr);
        hipLaunchKernelGGL(gemm_nt_128, dim3(8, 32), dim3(256), 0, stream,
                           scores, Hn, efc2_w, Hn, efc2_b, wtmp, Hn, (_Float16*)nullptr, (_Float16*)nullptr);
        hipLaunchKernelGGL(gemm_nt_128, dim3(8, 32), dim3(256), 0, stream,
                           wtmp, Hn, efc3_w, Hn, efc3_b, (float*)nullptr, Hn,
                           bufhi + (size_t)c * 4096 * 1024, buflo + (size_t)c * 4096 * 1024);
    }

    // ---- Split encoder LSTM weights into slot0/slot1 ----
    const int WN = 4194304;  // 4096*1024
    hipLaunchKernelGGL(wconv, dim3(4096), dim3(256), 0, stream, el1_wih, slot0,            slot0 + WN,     WN);
    hipLaunchKernelGGL(wconv, dim3(4096), dim3(256), 0, stream, el1_whh, slot0 + 2 * WN,   slot0 + 3 * WN, WN);
    hipLaunchKernelGGL(wconv, dim3(4096), dim3(256), 0, stream, el2_wih, slot1,            slot1 + WN,     WN);
    hipLaunchKernelGGL(wconv, dim3(4096), dim3(256), 0, stream, el2_whh, slot1 + 2 * WN,   slot1 + 3 * WN, WN);

    // ---- Zero states ----
    hipMemsetAsync(zbase, 0, zbytes, stream);

    // ---- Encoder LSTMs (fused l1+l2 per step, plane ping-pong) ----
    _Float16 *h1hiC = h1hiA, *h1loC = h1loA, *h1hiN = h1hiB, *h1loN = h1loB;
    _Float16 *h2hiC = h2hiA, *h2loC = h2loA, *h2hiN = h2hiB, *h2loN = h2loB;
    _Float16* tp;
    for (int t = 0; t < Tn; ++t) {
        hipLaunchKernelGGL(lstm_mfma, dim3(64, 4), dim3(256), 0, stream,
                           bufhi + (size_t)t * Hn, buflo + (size_t)t * Hn, TH,
                           h1hiC, h1loC, slot0, el1_bih, el1_bhh, c1,
                           (float*)nullptr, h1hiN, h1loN);
        tp = h1hiC; h1hiC = h1hiN; h1hiN = tp;
        tp = h1loC; h1loC = h1loN; h1loN = tp;
        hipLaunchKernelGGL(lstm_mfma, dim3(64, 4), dim3(256), 0, stream,
                           h1hiC, h1loC, Hn,
                           h2hiC, h2loC, slot1, el2_bih, el2_bhh, c2,
                           h2f, h2hiN, h2loN);
        tp = h2hiC; h2hiC = h2hiN; h2hiN = tp;
        tp = h2loC; h2loC = h2loN; h2loN = tp;
    }

    // ---- Split decoder LSTM weights (overwrite slots) ----
    hipLaunchKernelGGL(wconv, dim3(4096), dim3(256), 0, stream, dl1_wih, slot0,            slot0 + WN,     WN);
    hipLaunchKernelGGL(wconv, dim3(4096), dim3(256), 0, stream, dl1_whh, slot0 + 2 * WN,   slot0 + 3 * WN, WN);
    hipLaunchKernelGGL(wconv, dim3(4096), dim3(256), 0, stream, dl2_wih, slot1,            slot1 + WN,     WN);
    hipLaunchKernelGGL(wconv, dim3(4096), dim3(256), 0, stream, dl2_whh, slot1 + 2 * WN,   slot1 + 3 * WN, WN);

    // ---- Zero decoded output ----
    hipMemsetAsync(out, 0, (size_t)out_size * sizeof(float), stream);

    // ---- Decoder: 16 autoregressive steps ----
    for (int it = 0; it < DELTAn; ++it) {
        const _Float16* xh = (it == 0) ? h2hiC : embhi;
        const _Float16* xl = (it == 0) ? h2loC : emblo;
        hipLaunchKernelGGL(lstm_mfma, dim3(64, 4), dim3(256), 0, stream,
                           xh, xl, Hn, h1hiC, h1loC, slot0, dl1_bih, dl1_bhh, c1,
                           (float*)nullptr, h1hiN, h1loN);
        tp = h1hiC; h1hiC = h1hiN; h1hiN = tp;
        tp = h1loC; h1loC = h1loN; h1loN = tp;
        hipLaunchKernelGGL(lstm_mfma, dim3(64, 4), dim3(256), 0, stream,
                           h1hiC, h1loC, Hn, h2hiC, h2loC, slot1, dl2_bih, dl2_bhh, c2,
                           h2f, h2hiN, h2loN);
        tp = h2hiC; h2hiC = h2hiN; h2hiN = tp;
        tp = h2loC; h2loC = h2loN; h2loN = tp;

        hipLaunchKernelGGL(gemm_nt, dim3(16, 4), dim3(256), 0, stream,
                           h2f, Hn, dfc1_w, Hn, dfc1_b, f1buf, Hn);
        hipLaunchKernelGGL(gemm_nt, dim3(16, 4), dim3(256), 0, stream,
                           f1buf, Hn, dfc2_w, Hn, dfc2_b, f2buf, Hn);
        hipLaunchKernelGGL(gemm_nt_128, dim3(128, 2), dim3(256), 0, stream,
                           f2buf, Hn, dfc3_w, Hn, dfc3_b, scores, Vn, (_Float16*)nullptr, (_Float16*)nullptr);
        hipLaunchKernelGGL(beam_kernel, dim3(Bn), dim3(256), 0, stream,
                           scores, out, embhi, emblo, fqw_w, fqw_b, fql_w, fql_b,
                           it, (it == 0) ? Kn : 1);
    }
}

// Round 5
// 12555.846 us; speedup vs baseline: 3.1408x; 1.3860x over previous
//
#include <hip/hip_runtime.h>
#include <math.h>

// Problem constants
#define Hn     1024
#define Bn     256
#define Tn     128
#define Vn     16384
#define DELTAn 16
#define Kn     5
#define QLn    128

typedef _Float16 h8 __attribute__((ext_vector_type(8)));
typedef _Float16 h4 __attribute__((ext_vector_type(4)));
typedef float    f32x4 __attribute__((ext_vector_type(4)));

#define MFMA16(a, b, c) __builtin_amdgcn_mfma_f32_16x16x32_f16(a, b, c, 0, 0, 0)

// Per-matrix fragment region size (N=4096, K=1024): 256 gb * 32 ks * 2 planes * 512
#define WFRAG_4096 8388608

// ---------------------------------------------------------------------------
// Fragment-shuffle weight conversion: W (N x 1024 fp32, row-major) ->
// frag layout: chunk (gb, ks) = 64 lanes x 8 f16, hi plane then lo plane.
// lane l holds W[gb*16 + (l&15)][ks*32 + (l>>4)*8 + j], j=0..7.
// One wave per (gb, ks) chunk. ngb = N/16.
// ---------------------------------------------------------------------------
__global__ __launch_bounds__(256) void wconv_frag(
    const float* __restrict__ W, _Float16* __restrict__ wf, int ngb)
{
    int wid  = (blockIdx.x * 256 + threadIdx.x) >> 6;
    int lane = threadIdx.x & 63;
    int gb = wid >> 5, ks = wid & 31;
    if (gb >= ngb) return;
    const float* src = W + (size_t)(gb * 16 + (lane & 15)) * 1024 + ks * 32 + (lane >> 4) * 8;
    float4 v0 = *(const float4*)src;
    float4 v1 = *(const float4*)(src + 4);
    float vv[8] = {v0.x, v0.y, v0.z, v0.w, v1.x, v1.y, v1.z, v1.w};
    h8 vh, vl;
    #pragma unroll
    for (int j = 0; j < 8; ++j) {
        _Float16 hh = (_Float16)vv[j];
        vh[j] = hh;
        vl[j] = (_Float16)(vv[j] - (float)hh);
    }
    _Float16* dst = wf + ((size_t)(gb * 32 + ks) * 2) * 512 + lane * 8;
    *(h8*)dst        = vh;
    *(h8*)(dst + 512) = vl;
}

// ---------------------------------------------------------------------------
// fp32 GEMM: Y = A @ W^T + bias (64x64 tile). Decoder dfc1/dfc2.
// Optional f16 hi/lo plane output (dfc2 -> dfc3 feed).
// ---------------------------------------------------------------------------
__global__ __launch_bounds__(256) void gemm_nt(
    const float* __restrict__ A, int lda, const float* __restrict__ W, int K1,
    const float* __restrict__ bias1, float* __restrict__ Y, int ldy,
    _Float16* __restrict__ yhi, _Float16* __restrict__ ylo)
{
    __shared__ float As[16][68];
    __shared__ float Bs[16][68];
    const int bm  = blockIdx.y << 6;
    const int bn  = blockIdx.x << 6;
    const int tid = threadIdx.x;
    const int tx  = (tid & 15) << 2;
    const int ty  = (tid >> 4) << 2;
    const int lm  = tid >> 2;
    const int lk  = (tid & 3) << 2;

    float acc[4][4] = {};
    const float* arow = A + (size_t)(bm + lm) * lda + lk;
    const float* brow = W + (size_t)(bn + lm) * K1  + lk;

    for (int kt = 0; kt < K1; kt += 16) {
        float4 av = *(const float4*)(arow + kt);
        float4 bv = *(const float4*)(brow + kt);
        __syncthreads();
        As[lk + 0][lm] = av.x; As[lk + 1][lm] = av.y;
        As[lk + 2][lm] = av.z; As[lk + 3][lm] = av.w;
        Bs[lk + 0][lm] = bv.x; Bs[lk + 1][lm] = bv.y;
        Bs[lk + 2][lm] = bv.z; Bs[lk + 3][lm] = bv.w;
        __syncthreads();
        #pragma unroll
        for (int k = 0; k < 16; ++k) {
            float4 a = *(const float4*)(&As[k][ty]);
            float4 b = *(const float4*)(&Bs[k][tx]);
            acc[0][0] += a.x * b.x; acc[0][1] += a.x * b.y;
            acc[0][2] += a.x * b.z; acc[0][3] += a.x * b.w;
            acc[1][0] += a.y * b.x; acc[1][1] += a.y * b.y;
            acc[1][2] += a.y * b.z; acc[1][3] += a.y * b.w;
            acc[2][0] += a.z * b.x; acc[2][1] += a.z * b.y;
            acc[2][2] += a.z * b.z; acc[2][3] += a.z * b.w;
            acc[3][0] += a.w * b.x; acc[3][1] += a.w * b.y;
            acc[3][2] += a.w * b.z; acc[3][3] += a.w * b.w;
        }
    }

    const int n = bn + tx;
    #pragma unroll
    for (int i = 0; i < 4; ++i) {
        float4 v = make_float4(acc[i][0] + bias1[n],     acc[i][1] + bias1[n + 1],
                               acc[i][2] + bias1[n + 2], acc[i][3] + bias1[n + 3]);
        size_t ro = (size_t)(bm + ty + i) * ldy + n;
        if (yhi) {
            h4 vh, vl;
            float vs[4] = {v.x, v.y, v.z, v.w};
            #pragma unroll
            for (int j = 0; j < 4; ++j) {
                _Float16 hh = (_Float16)vs[j];
                vh[j] = hh;
                vl[j] = (_Float16)(vs[j] - (float)hh);
            }
            *(h4*)(yhi + ro) = vh;
            *(h4*)(ylo + ro) = vl;
        } else {
            *(float4*)(Y + ro) = v;
        }
    }
}

// ---------------------------------------------------------------------------
// Big-tile fp32 GEMM: 128x128 tile, 8x8 microtile, plane output option.
// Used only for efc1 (K=64).
// ---------------------------------------------------------------------------
__global__ __launch_bounds__(256) void gemm_nt_128(
    const float* __restrict__ A, int lda, const float* __restrict__ W, int K,
    const float* __restrict__ bias, float* __restrict__ Y, int ldy,
    _Float16* __restrict__ yhi, _Float16* __restrict__ ylo)
{
    __shared__ float As[16 * 132];
    __shared__ float Bs[16 * 132];
    const int bm   = blockIdx.y << 7;
    const int bn   = blockIdx.x << 7;
    const int tid  = threadIdx.x;
    const int tx   = (tid & 15) << 3;
    const int ty   = (tid >> 4) << 3;
    const int lrow = tid >> 1;
    const int lk   = (tid & 1) << 3;

    float acc[8][8] = {};
    const float* arow = A + (size_t)(bm + lrow) * lda + lk;
    const float* brow = W + (size_t)(bn + lrow) * K   + lk;

    for (int kt = 0; kt < K; kt += 16) {
        float4 a0 = *(const float4*)(arow + kt);
        float4 a1 = *(const float4*)(arow + kt + 4);
        float4 b0 = *(const float4*)(brow + kt);
        float4 b1 = *(const float4*)(brow + kt + 4);
        __syncthreads();
        As[(lk + 0) * 132 + lrow] = a0.x; As[(lk + 1) * 132 + lrow] = a0.y;
        As[(lk + 2) * 132 + lrow] = a0.z; As[(lk + 3) * 132 + lrow] = a0.w;
        As[(lk + 4) * 132 + lrow] = a1.x; As[(lk + 5) * 132 + lrow] = a1.y;
        As[(lk + 6) * 132 + lrow] = a1.z; As[(lk + 7) * 132 + lrow] = a1.w;
        Bs[(lk + 0) * 132 + lrow] = b0.x; Bs[(lk + 1) * 132 + lrow] = b0.y;
        Bs[(lk + 2) * 132 + lrow] = b0.z; Bs[(lk + 3) * 132 + lrow] = b0.w;
        Bs[(lk + 4) * 132 + lrow] = b1.x; Bs[(lk + 5) * 132 + lrow] = b1.y;
        Bs[(lk + 6) * 132 + lrow] = b1.z; Bs[(lk + 7) * 132 + lrow] = b1.w;
        __syncthreads();
        #pragma unroll
        for (int k = 0; k < 16; ++k) {
            float4 x0 = *(const float4*)(As + k * 132 + ty);
            float4 x1 = *(const float4*)(As + k * 132 + ty + 4);
            float4 y0 = *(const float4*)(Bs + k * 132 + tx);
            float4 y1 = *(const float4*)(Bs + k * 132 + tx + 4);
            float av[8] = {x0.x, x0.y, x0.z, x0.w, x1.x, x1.y, x1.z, x1.w};
            float bv[8] = {y0.x, y0.y, y0.z, y0.w, y1.x, y1.y, y1.z, y1.w};
            #pragma unroll
            for (int i = 0; i < 8; ++i)
                #pragma unroll
                for (int j = 0; j < 8; ++j)
                    acc[i][j] += av[i] * bv[j];
        }
    }

    #pragma unroll
    for (int i = 0; i < 8; ++i) {
        size_t ro = (size_t)(bm + ty + i) * ldy + bn + tx;
        if (yhi) {
            h8 vh, vl;
            #pragma unroll
            for (int j = 0; j < 8; ++j) {
                float v = acc[i][j] + bias[bn + tx + j];
                _Float16 hh = (_Float16)v;
                vh[j] = hh;
                vl[j] = (_Float16)(v - (float)hh);
            }
            *(h8*)(yhi + ro) = vh;
            *(h8*)(ylo + ro) = vl;
        } else {
            float4 v0 = make_float4(acc[i][0] + bias[bn + tx + 0], acc[i][1] + bias[bn + tx + 1],
                                    acc[i][2] + bias[bn + tx + 2], acc[i][3] + bias[bn + tx + 3]);
            float4 v1 = make_float4(acc[i][4] + bias[bn + tx + 4], acc[i][5] + bias[bn + tx + 5],
                                    acc[i][6] + bias[bn + tx + 6], acc[i][7] + bias[bn + tx + 7]);
            *(float4*)(Y + ro)     = v0;
            *(float4*)(Y + ro + 4) = v1;
        }
    }
}

// ---------------------------------------------------------------------------
// Split-f16 MFMA GEMM (K=1024): Y = Aplanes @ Wfrag^T + bias.
// Grid (N/64, M/64), 256 threads (4 waves). Wave: 16 m x 64 n.
// A staged via LDS (64 rows x 64 k per super-iter); B direct from frag layout.
// Output fp32 or hi/lo planes.
// ---------------------------------------------------------------------------
__global__ __launch_bounds__(256) void gemm_mfma(
    const _Float16* __restrict__ Ahi, const _Float16* __restrict__ Alo, long long lda,
    const _Float16* __restrict__ wf, const float* __restrict__ bias,
    float* __restrict__ Y, long long ldy,
    _Float16* __restrict__ yhi, _Float16* __restrict__ ylo)
{
    __shared__ _Float16 lds[2][64 * 72];
    const int tid  = threadIdx.x;
    const int bn   = blockIdx.x << 6;
    const int bm   = blockIdx.y << 6;
    const int lane = tid & 63, wv = tid >> 6;
    const int l15  = lane & 15, quad = lane >> 4;
    const int r    = tid >> 2, kq = (tid & 3) << 4;

    f32x4 acc[4];
    #pragma unroll
    for (int nf = 0; nf < 4; ++nf) acc[nf] = (f32x4){0.f, 0.f, 0.f, 0.f};

    h8 p0h, p1h, p0l, p1l;
    {
        size_t off = (size_t)(bm + r) * lda + kq;
        p0h = *(const h8*)(Ahi + off); p1h = *(const h8*)(Ahi + off + 8);
        p0l = *(const h8*)(Alo + off); p1l = *(const h8*)(Alo + off + 8);
    }

    for (int si = 0; si < 16; ++si) {
        __syncthreads();
        *(h8*)(&lds[0][r * 72 + kq])     = p0h;
        *(h8*)(&lds[0][r * 72 + kq + 8]) = p1h;
        *(h8*)(&lds[1][r * 72 + kq])     = p0l;
        *(h8*)(&lds[1][r * 72 + kq + 8]) = p1l;
        __syncthreads();
        {
            int sn = (si + 1 < 16) ? si + 1 : si;
            size_t off = (size_t)(bm + r) * lda + (sn << 6) + kq;
            p0h = *(const h8*)(Ahi + off); p1h = *(const h8*)(Ahi + off + 8);
            p0l = *(const h8*)(Alo + off); p1l = *(const h8*)(Alo + off + 8);
        }
        #pragma unroll
        for (int sub = 0; sub < 2; ++sub) {
            int ks = (si << 1) + sub;
            h8 axh = *(const h8*)(&lds[0][(wv * 16 + l15) * 72 + sub * 32 + quad * 8]);
            h8 axl = *(const h8*)(&lds[1][(wv * 16 + l15) * 72 + sub * 32 + quad * 8]);
            #pragma unroll
            for (int nf = 0; nf < 4; ++nf) {
                int gb = (bn >> 4) + nf;
                const _Float16* bp = wf + ((size_t)(gb * 32 + ks) * 2) * 512 + lane * 8;
                h8 bh = *(const h8*)bp;
                h8 bl = *(const h8*)(bp + 512);
                acc[nf] = MFMA16(axh, bh, acc[nf]);
                acc[nf] = MFMA16(axh, bl, acc[nf]);
                acc[nf] = MFMA16(axl, bh, acc[nf]);
            }
        }
    }

    #pragma unroll
    for (int nf = 0; nf < 4; ++nf) {
        int col = bn + nf * 16 + l15;
        float bv = bias[col];
        #pragma unroll
        for (int rr = 0; rr < 4; ++rr) {
            int m = bm + wv * 16 + quad * 4 + rr;
            float v = acc[nf][rr] + bv;
            size_t ro = (size_t)m * ldy + col;
            if (yhi) {
                _Float16 hh = (_Float16)v;
                yhi[ro] = hh;
                ylo[ro] = (_Float16)(v - (float)hh);
            } else {
                Y[ro] = v;
            }
        }
    }
}

// ---------------------------------------------------------------------------
// Fused split-f16 MFMA LSTM step. Grid (64 jt, 4 bt, nz); blockIdx.z picks
// the param set (wavefront-fused encoder: z=0 -> layer1 t, z=1 -> layer2 t-1).
// Set with wf==nullptr -> no-op. B-frags direct from frag-layout weights
// (wih' at wf, whh' at wf+WFRAG_4096); A (x then hprev) staged via LDS.
// Epilogue: gates in-register, update c, write h planes (+optional fp32 h).
// ---------------------------------------------------------------------------
struct LstmSet {
    const _Float16 *xhi, *xlo; long long ldx;
    const _Float16 *hphi, *hplo;
    const _Float16 *wf;
    const float *bih, *bhh;
    float *c, *hf;
    _Float16 *hohi, *holo;
};

__global__ __launch_bounds__(256) void lstm_mfma2(LstmSet s0, LstmSet s1)
{
    LstmSet s = (blockIdx.z == 0) ? s0 : s1;
    if (s.wf == nullptr) return;
    __shared__ _Float16 lds[2][64 * 72];
    const int tid  = threadIdx.x;
    const int jt   = blockIdx.x;
    const int bm   = blockIdx.y << 6;
    const int lane = tid & 63, wv = tid >> 6;
    const int l15  = lane & 15, quad = lane >> 4;
    const int r    = tid >> 2, kq = (tid & 3) << 4;

    f32x4 acc[4];
    #pragma unroll
    for (int nf = 0; nf < 4; ++nf) acc[nf] = (f32x4){0.f, 0.f, 0.f, 0.f};

    h8 p0h, p1h, p0l, p1l;
    {
        size_t off = (size_t)(bm + r) * s.ldx + kq;
        p0h = *(const h8*)(s.xhi + off); p1h = *(const h8*)(s.xhi + off + 8);
        p0l = *(const h8*)(s.xlo + off); p1l = *(const h8*)(s.xlo + off + 8);
    }

    for (int si = 0; si < 32; ++si) {
        __syncthreads();
        *(h8*)(&lds[0][r * 72 + kq])     = p0h;
        *(h8*)(&lds[0][r * 72 + kq + 8]) = p1h;
        *(h8*)(&lds[1][r * 72 + kq])     = p0l;
        *(h8*)(&lds[1][r * 72 + kq + 8]) = p1l;
        __syncthreads();
        {   // prefetch next super-iter's A tile
            int sn = (si + 1 < 32) ? si + 1 : si;
            int ph = sn >> 4;
            const _Float16* xh = ph ? s.hphi : s.xhi;
            const _Float16* xl = ph ? s.hplo : s.xlo;
            long long ld = ph ? Hn : s.ldx;
            size_t off = (size_t)(bm + r) * ld + ((sn & 15) << 6) + kq;
            p0h = *(const h8*)(xh + off); p1h = *(const h8*)(xh + off + 8);
            p0l = *(const h8*)(xl + off); p1l = *(const h8*)(xl + off + 8);
        }
        const _Float16* wb = s.wf + (size_t)(si >> 4) * WFRAG_4096;
        const int ksbase = (si & 15) << 1;
        #pragma unroll
        for (int sub = 0; sub < 2; ++sub) {
            int ks = ksbase + sub;
            h8 axh = *(const h8*)(&lds[0][(wv * 16 + l15) * 72 + sub * 32 + quad * 8]);
            h8 axl = *(const h8*)(&lds[1][(wv * 16 + l15) * 72 + sub * 32 + quad * 8]);
            #pragma unroll
            for (int nf = 0; nf < 4; ++nf) {
                int gb = nf * 64 + jt;
                const _Float16* bp = wb + ((size_t)(gb * 32 + ks) * 2) * 512 + lane * 8;
                h8 bh = *(const h8*)bp;
                h8 bl = *(const h8*)(bp + 512);
                acc[nf] = MFMA16(axh, bh, acc[nf]);
                acc[nf] = MFMA16(axh, bl, acc[nf]);
                acc[nf] = MFMA16(axl, bh, acc[nf]);
            }
        }
    }

    // Epilogue: lane holds all 4 gates for 4 batch rows x col j=l15.
    float bs[4];
    #pragma unroll
    for (int nf = 0; nf < 4; ++nf) {
        int br = nf * Hn + (jt << 4) + l15;
        bs[nf] = s.bih[br] + s.bhh[br];
    }
    #pragma unroll
    for (int rr = 0; rr < 4; ++rr) {
        int m = (wv << 4) + (quad << 2) + rr;
        size_t idx = (size_t)(bm + m) * Hn + (jt << 4) + l15;
        float gi = acc[0][rr] + bs[0];
        float gf = acc[1][rr] + bs[1];
        float gg = acc[2][rr] + bs[2];
        float go = acc[3][rr] + bs[3];
        float cv = s.c[idx];
        float si_ = 1.0f / (1.0f + expf(-gi));
        float sf  = 1.0f / (1.0f + expf(-gf));
        float so  = 1.0f / (1.0f + expf(-go));
        float cn = sf * cv + si_ * tanhf(gg);
        float hn = so * tanhf(cn);
        s.c[idx] = cn;
        if (s.hf) s.hf[idx] = hn;
        _Float16 hh = (_Float16)hn;
        s.hohi[idx] = hh;
        s.holo[idx] = (_Float16)(hn - (float)hh);
    }
}

// ---------------------------------------------------------------------------
// Per-row top-k over V=16384; decoded indices + next-step embedding planes.
// ---------------------------------------------------------------------------
__global__ __launch_bounds__(256) void beam_kernel(
    const float* __restrict__ scores, float* __restrict__ decoded,
    _Float16* __restrict__ embhi, _Float16* __restrict__ emblo,
    const float* __restrict__ fqw_w, const float* __restrict__ fqw_b,
    const float* __restrict__ fql_w, const float* __restrict__ fql_b,
    int step, int kcur)
{
    __shared__ float svals[256];
    __shared__ int   sidx[256];
    __shared__ int   sel[Kn];
    const int b   = blockIdx.x;
    const int tid = threadIdx.x;
    const float* row = scores + (size_t)b * Vn;

    for (int rr = 0; rr < kcur; ++rr) {
        float best = -INFINITY;
        int   bidx = Vn;
        for (int i = tid; i < Vn; i += 256) {
            bool skip = false;
            for (int q = 0; q < rr; ++q) if (sel[q] == i) skip = true;
            float v = row[i];
            if (!skip && v > best) { best = v; bidx = i; }
        }
        svals[tid] = best; sidx[tid] = bidx;
        __syncthreads();
        for (int s = 128; s > 0; s >>= 1) {
            if (tid < s) {
                float v2 = svals[tid + s]; int i2 = sidx[tid + s];
                if (v2 > svals[tid] || (v2 == svals[tid] && i2 < sidx[tid])) {
                    svals[tid] = v2; sidx[tid] = i2;
                }
            }
            __syncthreads();
        }
        if (tid == 0) sel[rr] = sidx[0];
        __syncthreads();
    }

    if (tid < kcur) {
        int s_ = sel[tid];
        int fw = s_ / QLn, fl = s_ % QLn;
        float* dp = decoded + ((size_t)(b * DELTAn + step) * Kn + tid) * 2;
        dp[0] = (float)fl;
        dp[1] = (float)fw;
    }

    const int fw0 = sel[0] / QLn;
    const int fl0 = sel[0] % QLn;
    for (int o = tid; o < 512; o += 256) {
        float v0 = fqw_w[o * QLn + fw0] + fqw_b[o];
        float v1 = fql_w[o * QLn + fl0] + fql_b[o];
        _Float16 h0 = (_Float16)v0;
        _Float16 h1 = (_Float16)v1;
        size_t i0 = (size_t)b * Hn + o;
        embhi[i0]       = h0; emblo[i0]       = (_Float16)(v0 - (float)h0);
        embhi[i0 + 512] = h1; emblo[i0 + 512] = (_Float16)(v1 - (float)h1);
    }
}

// ---------------------------------------------------------------------------
extern "C" void kernel_launch(void* const* d_in, const int* in_sizes, int n_in,
                              void* d_out, int out_size, void* d_ws, size_t ws_size,
                              hipStream_t stream)
{
    int ii = 0;
    const float* x       = (const float*)d_in[ii++];
    const float* efc1_w  = (const float*)d_in[ii++];
    const float* efc1_b  = (const float*)d_in[ii++];
    const float* efc2_w  = (const float*)d_in[ii++];
    const float* efc2_b  = (const float*)d_in[ii++];
    const float* efc3_w  = (const float*)d_in[ii++];
    const float* efc3_b  = (const float*)d_in[ii++];
    const float* el1_wih = (const float*)d_in[ii++];
    const float* el1_whh = (const float*)d_in[ii++];
    const float* el1_bih = (const float*)d_in[ii++];
    const float* el1_bhh = (const float*)d_in[ii++];
    const float* el2_wih = (const float*)d_in[ii++];
    const float* el2_whh = (const float*)d_in[ii++];
    const float* el2_bih = (const float*)d_in[ii++];
    const float* el2_bhh = (const float*)d_in[ii++];
    const float* dl1_wih = (const float*)d_in[ii++];
    const float* dl1_whh = (const float*)d_in[ii++];
    const float* dl1_bih = (const float*)d_in[ii++];
    const float* dl1_bhh = (const float*)d_in[ii++];
    const float* dl2_wih = (const float*)d_in[ii++];
    const float* dl2_whh = (const float*)d_in[ii++];
    const float* dl2_bih = (const float*)d_in[ii++];
    const float* dl2_bhh = (const float*)d_in[ii++];
    const float* dfc1_w  = (const float*)d_in[ii++];
    const float* dfc1_b  = (const float*)d_in[ii++];
    const float* dfc2_w  = (const float*)d_in[ii++];
    const float* dfc2_b  = (const float*)d_in[ii++];
    const float* dfc3_w  = (const float*)d_in[ii++];
    const float* dfc3_b  = (const float*)d_in[ii++];
    const float* fqw_w   = (const float*)d_in[ii++];
    const float* fqw_b   = (const float*)d_in[ii++];
    const float* fql_w   = (const float*)d_in[ii++];
    const float* fql_b   = (const float*)d_in[ii++];

    float* out = (float*)d_out;

    // ---- Workspace layout (~237 MB) ----
    char* p = (char*)d_ws;
    auto alloc = [&](size_t bytes) { char* q = p; p += (bytes + 255) & ~(size_t)255; return q; };
    _Float16* bufhi = (_Float16*)alloc((size_t)32768 * 1024 * 2);  // e3 hi; later dfc3' frags
    _Float16* buflo = (_Float16*)alloc((size_t)32768 * 1024 * 2);  // e3 lo
    _Float16* slot0 = (_Float16*)alloc((size_t)2 * WFRAG_4096 * 2); // l1 frags (wih'+whh')
    _Float16* slot1 = (_Float16*)alloc((size_t)2 * WFRAG_4096 * 2); // l2 frags
    _Float16* efw2  = (_Float16*)alloc((size_t)2097152 * 2);        // efc2' frags
    _Float16* efw3  = (_Float16*)alloc((size_t)2097152 * 2);        // efc3' frags
    float*    scores= (float*)alloc((size_t)256 * Vn * 4);          // fp32; t1 planes in FC
    char*  zbase = p;                                               // zero block:
    float* h2f   = (float*)alloc((size_t)256 * Hn * 4);
    float* c1    = (float*)alloc((size_t)256 * Hn * 4);
    float* c2    = (float*)alloc((size_t)256 * Hn * 4);
    _Float16* h1hiA = (_Float16*)alloc((size_t)256 * Hn * 2);
    _Float16* h1loA = (_Float16*)alloc((size_t)256 * Hn * 2);
    _Float16* h2hiA = (_Float16*)alloc((size_t)256 * Hn * 2);
    _Float16* h2loA = (_Float16*)alloc((size_t)256 * Hn * 2);
    size_t zbytes = (size_t)(p - zbase);
    _Float16* h1hiB = (_Float16*)alloc((size_t)256 * Hn * 2);
    _Float16* h1loB = (_Float16*)alloc((size_t)256 * Hn * 2);
    _Float16* h2hiB = (_Float16*)alloc((size_t)256 * Hn * 2);
    _Float16* h2loB = (_Float16*)alloc((size_t)256 * Hn * 2);
    float*    f1buf = (float*)alloc((size_t)256 * Hn * 4);
    _Float16* f2hi  = (_Float16*)alloc((size_t)256 * Hn * 2);
    _Float16* f2lo  = (_Float16*)alloc((size_t)256 * Hn * 2);
    _Float16* embhi = (_Float16*)alloc((size_t)256 * Hn * 2);
    _Float16* emblo = (_Float16*)alloc((size_t)256 * Hn * 2);

    // FC-phase temps (regions dead during FC):
    _Float16* t1hi = (_Float16*)scores;            // 4096x1024 planes in scores
    _Float16* t1lo = t1hi + (size_t)4096 * 1024;
    _Float16* t2hi = slot0;                        // 4096x1024 planes in slot0
    _Float16* t2lo = t2hi + (size_t)4096 * 1024;
    _Float16* dfc3f = bufhi;                       // dfc3' frags (67.1 MB) after encoder

    const long long TH = (long long)Tn * Hn;

    // ---- efc2'/efc3' fragment conversion ----
    hipLaunchKernelGGL(wconv_frag, dim3(512), dim3(256), 0, stream, efc2_w, efw2, 64);
    hipLaunchKernelGGL(wconv_frag, dim3(512), dim3(256), 0, stream, efc3_w, efw3, 64);

    // ---- Encoder FC chain, 8 chunks of 4096 rows ----
    for (int c = 0; c < 8; ++c) {
        const float* xc = x + (size_t)c * 4096 * 64;
        size_t ofs = (size_t)c * 4096 * 1024;
        hipLaunchKernelGGL(gemm_nt_128, dim3(8, 32), dim3(256), 0, stream,
                           xc, 64, efc1_w, 64, efc1_b, (float*)nullptr, Hn, t1hi, t1lo);
        hipLaunchKernelGGL(gemm_mfma, dim3(16, 64), dim3(256), 0, stream,
                           t1hi, t1lo, (long long)Hn, efw2, efc2_b,
                           (float*)nullptr, (long long)Hn, t2hi, t2lo);
        hipLaunchKernelGGL(gemm_mfma, dim3(16, 64), dim3(256), 0, stream,
                           t2hi, t2lo, (long long)Hn, efw3, efc3_b,
                           (float*)nullptr, (long long)Hn, bufhi + ofs, buflo + ofs);
    }

    // ---- Encoder LSTM weight frags ----
    hipLaunchKernelGGL(wconv_frag, dim3(2048), dim3(256), 0, stream, el1_wih, slot0, 256);
    hipLaunchKernelGGL(wconv_frag, dim3(2048), dim3(256), 0, stream, el1_whh, slot0 + WFRAG_4096, 256);
    hipLaunchKernelGGL(wconv_frag, dim3(2048), dim3(256), 0, stream, el2_wih, slot1, 256);
    hipLaunchKernelGGL(wconv_frag, dim3(2048), dim3(256), 0, stream, el2_whh, slot1 + WFRAG_4096, 256);

    hipMemsetAsync(zbase, 0, zbytes, stream);

    // ---- Encoder LSTMs: wavefront-fused l1(t=d) + l2(t=d-1), 129 dispatches ----
    _Float16 *h1hiC = h1hiA, *h1loC = h1loA, *h1hiN = h1hiB, *h1loN = h1loB;
    _Float16 *h2hiC = h2hiA, *h2loC = h2loA, *h2hiN = h2hiB, *h2loN = h2loB;
    _Float16* tp;
    for (int d = 0; d <= Tn; ++d) {
        LstmSet s0 = {}, s1 = {};
        if (d < Tn) {
            s0.xhi = bufhi + (size_t)d * Hn; s0.xlo = buflo + (size_t)d * Hn; s0.ldx = TH;
            s0.hphi = h1hiC; s0.hplo = h1loC; s0.wf = slot0;
            s0.bih = el1_bih; s0.bhh = el1_bhh; s0.c = c1; s0.hf = nullptr;
            s0.hohi = h1hiN; s0.holo = h1loN;
        }
        if (d >= 1) {
            s1.xhi = h1hiC; s1.xlo = h1loC; s1.ldx = Hn;
            s1.hphi = h2hiC; s1.hplo = h2loC; s1.wf = slot1;
            s1.bih = el2_bih; s1.bhh = el2_bhh; s1.c = c2; s1.hf = nullptr;
            s1.hohi = h2hiN; s1.holo = h2loN;
        }
        hipLaunchKernelGGL(lstm_mfma2, dim3(64, 4, 2), dim3(256), 0, stream, s0, s1);
        if (d < Tn)  { tp = h1hiC; h1hiC = h1hiN; h1hiN = tp;
                       tp = h1loC; h1loC = h1loN; h1loN = tp; }
        if (d >= 1)  { tp = h2hiC; h2hiC = h2hiN; h2hiN = tp;
                       tp = h2loC; h2loC = h2loN; h2loN = tp; }
    }

    // ---- Decoder weight frags (slots reused; dfc3' into dead bufhi) ----
    hipLaunchKernelGGL(wconv_frag, dim3(2048), dim3(256), 0, stream, dl1_wih, slot0, 256);
    hipLaunchKernelGGL(wconv_frag, dim3(2048), dim3(256), 0, stream, dl1_whh, slot0 + WFRAG_4096, 256);
    hipLaunchKernelGGL(wconv_frag, dim3(2048), dim3(256), 0, stream, dl2_wih, slot1, 256);
    hipLaunchKernelGGL(wconv_frag, dim3(2048), dim3(256), 0, stream, dl2_whh, slot1 + WFRAG_4096, 256);
    hipLaunchKernelGGL(wconv_frag, dim3(8192), dim3(256), 0, stream, dfc3_w, dfc3f, 1024);

    hipMemsetAsync(out, 0, (size_t)out_size * sizeof(float), stream);

    // ---- Decoder: 16 autoregressive steps ----
    for (int it = 0; it < DELTAn; ++it) {
        LstmSet s0 = {}, sx = {};
        s0.xhi = (it == 0) ? h2hiC : embhi;
        s0.xlo = (it == 0) ? h2loC : emblo;
        s0.ldx = Hn;
        s0.hphi = h1hiC; s0.hplo = h1loC; s0.wf = slot0;
        s0.bih = dl1_bih; s0.bhh = dl1_bhh; s0.c = c1; s0.hf = nullptr;
        s0.hohi = h1hiN; s0.holo = h1loN;
        hipLaunchKernelGGL(lstm_mfma2, dim3(64, 4, 1), dim3(256), 0, stream, s0, sx);
        tp = h1hiC; h1hiC = h1hiN; h1hiN = tp;
        tp = h1loC; h1loC = h1loN; h1loN = tp;

        LstmSet s2 = {};
        s2.xhi = h1hiC; s2.xlo = h1loC; s2.ldx = Hn;
        s2.hphi = h2hiC; s2.hplo = h2loC; s2.wf = slot1;
        s2.bih = dl2_bih; s2.bhh = dl2_bhh; s2.c = c2; s2.hf = h2f;
        s2.hohi = h2hiN; s2.holo = h2loN;
        hipLaunchKernelGGL(lstm_mfma2, dim3(64, 4, 1), dim3(256), 0, stream, s2, sx);
        tp = h2hiC; h2hiC = h2hiN; h2hiN = tp;
        tp = h2loC; h2loC = h2loN; h2loN = tp;

        hipLaunchKernelGGL(gemm_nt, dim3(16, 4), dim3(256), 0, stream,
                           h2f, Hn, dfc1_w, Hn, dfc1_b, f1buf, Hn,
                           (_Float16*)nullptr, (_Float16*)nullptr);
        hipLaunchKernelGGL(gemm_nt, dim3(16, 4), dim3(256), 0, stream,
                           f1buf, Hn, dfc2_w, Hn, dfc2_b, (float*)nullptr, Hn, f2hi, f2lo);
        hipLaunchKernelGGL(gemm_mfma, dim3(256, 4), dim3(256), 0, stream,
                           f2hi, f2lo, (long long)Hn, dfc3f, dfc3_b,
                           scores, (long long)Vn, (_Float16*)nullptr, (_Float16*)nullptr);
        hipLaunchKernelGGL(beam_kernel, dim3(Bn), dim3(256), 0, stream,
                           scores, out, embhi, emblo, fqw_w, fqw_b, fql_w, fql_b,
                           it, (it == 0) ? Kn : 1);
    }
}